// Round 1
// baseline (23505.971 us; speedup 1.0000x reference)
//
#include <hip/hip_runtime.h>
#include <hip/hip_bf16.h>
#include <cstdio>

// QuantGRU: T=512, B=64, I=H=1024.
// k_gemm_x precomputes all x-projections (parallel GEMM, bf16 MFMA).
// k_recurrent: persistent 256-WG kernel, device-wide flag barrier per step,
// recurrent weights resident in VGPRs (wave-K-split), pointwise in f32.

typedef short bf16x8 __attribute__((ext_vector_type(8)));
typedef float f32x4 __attribute__((ext_vector_type(4)));

#define NT 512
#define NB 64
#define NH 1024
#define NWG 256

// ws layout (bytes)
#define OFF_FLAGS 0UL
#define OFF_HBUF  4096UL                                   // 2 x 64x1024 bf16 = 256KB
#define OFF_WCAT  (OFF_HBUF + 2UL * NB * NH * 2)           // 3072x1024 bf16 = 6MB (Wri|Wii|Wni)
#define OFF_WH    (OFF_WCAT + 3UL * NH * NH * 2)           // 3 x 1024x1024 bf16 = 6MB (Wrh,Wih,Wnh)
#define OFF_GR    (OFF_WH   + 3UL * NH * NH * 2)           // 32768x1024 bf16 = 64MB
#define OFF_GI    (OFF_GR   + (unsigned long)NT * NB * NH * 2)
#define WS_NEED   (OFF_GI   + (unsigned long)NT * NB * NH * 2)   // ~140.3 MB

__device__ __forceinline__ float clampf(float x) { return fminf(fmaxf(x, -1.f), 1.f); }

__device__ __forceinline__ unsigned short f2bf(float x) {
  __hip_bfloat16 h = __float2bfloat16(x);
  union { __hip_bfloat16 h; unsigned short u; } cv;
  cv.h = h;
  return cv.u;
}
__device__ __forceinline__ float bf2f(unsigned short u) {
  return __uint_as_float(((unsigned)u) << 16);
}

// ---------------- kernel 0a: weights f32 -> bf16 --------------------------
__global__ void k_convert_weights(const float* __restrict__ wri, const float* __restrict__ wii,
                                  const float* __restrict__ wni, const float* __restrict__ wrh,
                                  const float* __restrict__ wih, const float* __restrict__ wnh,
                                  unsigned short* __restrict__ wcat, unsigned short* __restrict__ wh) {
  const long total = 6L * 1024 * 1024;
  long stride = (long)gridDim.x * blockDim.x * 4;
  for (long i = ((long)blockIdx.x * blockDim.x + threadIdx.x) * 4; i < total; i += stride) {
    int m = (int)(i >> 20);              // which matrix
    long off = i & 1048575L;
    const float* srcs[6] = {wri, wii, wni, wrh, wih, wnh};
    float4 v = *(const float4*)(srcs[m] + off);
    ushort4 o;
    o.x = f2bf(v.x); o.y = f2bf(v.y); o.z = f2bf(v.z); o.w = f2bf(v.w);
    unsigned short* dst = (m < 3) ? (wcat + ((long)m << 20) + off)
                                  : (wh + ((long)(m - 3) << 20) + off);
    *(ushort4*)dst = o;
  }
}

// ---------------- kernel 0b: h0 = bf16(clamp(state)) ----------------------
__global__ void k_clamp_convert(const float* __restrict__ src, unsigned short* __restrict__ dst, int n) {
  int i = ((int)blockIdx.x * blockDim.x + threadIdx.x) * 4;
  if (i < n) {
    float4 v = *(const float4*)(src + i);
    ushort4 o;
    o.x = f2bf(clampf(v.x)); o.y = f2bf(clampf(v.y));
    o.z = f2bf(clampf(v.z)); o.w = f2bf(clampf(v.w));
    *(ushort4*)(dst + i) = o;
  }
}

// ---------------- kernel 1: input projections GEMM ------------------------
// C[m,n] = clamp(X[m,:]) . Wcat[n,:] + bias_g[n%1024]
// M=32768 (t*64+b), N=3072 (gate-major), K=1024. 128x128 tile, BK=64, 4 waves.
#define BK 64
__launch_bounds__(256)
__global__ void k_gemm_x(const float* __restrict__ A,              // X f32 [32768][1024]
                         const unsigned short* __restrict__ Bw,    // Wcat bf16 [3072][1024]
                         unsigned short* __restrict__ gr, unsigned short* __restrict__ gi,
                         float* __restrict__ gni,                  // = d_out plane [32768][1024]
                         const float* __restrict__ br, const float* __restrict__ bi,
                         const float* __restrict__ bni) {
  __shared__ unsigned short As[128 * BK];
  __shared__ unsigned short Bs[128 * BK];

  int bid = blockIdx.x;
  int bm = bid / 24, bn = bid % 24;
  int tid = threadIdx.x;
  int lane = tid & 63, w = tid >> 6;
  int wm = w >> 1, wn = w & 1;

  long arow0 = (long)bm * 128;
  long brow0 = (long)bn * 128;

  f32x4 acc[4][4] = {};

  for (int kt = 0; kt < 1024; kt += BK) {
    __syncthreads();
#pragma unroll
    for (int it = 0; it < 4; ++it) {
      int f = it * 2048 + tid * 8;
      int r = f >> 6, c = f & 63;
      // A: f32 -> clamp -> bf16 pack
      const float* ap = A + (arow0 + r) * 1024 + kt + c;
      float4 v0 = *(const float4*)ap;
      float4 v1 = *(const float4*)(ap + 4);
      int4 p;
      p.x = (int)(f2bf(clampf(v0.x)) | ((unsigned)f2bf(clampf(v0.y)) << 16));
      p.y = (int)(f2bf(clampf(v0.z)) | ((unsigned)f2bf(clampf(v0.w)) << 16));
      p.z = (int)(f2bf(clampf(v1.x)) | ((unsigned)f2bf(clampf(v1.y)) << 16));
      p.w = (int)(f2bf(clampf(v1.z)) | ((unsigned)f2bf(clampf(v1.w)) << 16));
      *(int4*)(&As[f]) = p;
      // B: bf16 straight copy
      *(int4*)(&Bs[f]) = *(const int4*)(Bw + (brow0 + r) * 1024 + kt + c);
    }
    __syncthreads();
#pragma unroll
    for (int ks = 0; ks < 2; ++ks) {
      bf16x8 a[4], b[4];
#pragma unroll
      for (int fm = 0; fm < 4; ++fm)
        a[fm] = *(const bf16x8*)(&As[(wm * 64 + fm * 16 + (lane & 15)) * BK + ks * 32 + (lane >> 4) * 8]);
#pragma unroll
      for (int fn = 0; fn < 4; ++fn)
        b[fn] = *(const bf16x8*)(&Bs[(wn * 64 + fn * 16 + (lane & 15)) * BK + ks * 32 + (lane >> 4) * 8]);
#pragma unroll
      for (int fm = 0; fm < 4; ++fm)
#pragma unroll
        for (int fn = 0; fn < 4; ++fn)
          acc[fm][fn] = __builtin_amdgcn_mfma_f32_16x16x32_bf16(a[fm], b[fn], acc[fm][fn], 0, 0, 0);
    }
  }

  int g = bn >> 3;  // 0:r 1:i 2:ni (uniform per block)
  const float* bias = (g == 0) ? br : (g == 1) ? bi : bni;
#pragma unroll
  for (int fm = 0; fm < 4; ++fm) {
    long m = arow0 + wm * 64 + fm * 16 + (lane >> 4) * 4;
#pragma unroll
    for (int fn = 0; fn < 4; ++fn) {
      long n = brow0 + wn * 64 + fn * 16 + (lane & 15);
      long colg = n & 1023;
      float bv = bias[colg];
#pragma unroll
      for (int r2 = 0; r2 < 4; ++r2) {
        float v = acc[fm][fn][r2] + bv;
        long idx = (m + r2) * 1024 + colg;
        if (g == 0)      gr[idx] = f2bf(v);
        else if (g == 1) gi[idx] = f2bf(v);
        else             gni[idx] = clampf(v);   // pre-clamped ni (includes bias)
      }
    }
  }
}

// ---------------- kernel 2: persistent recurrence -------------------------
// 256 WGs x 256 threads. WG = (j = wg&63 hidden slice of 16, mb = wg>>6 batch quarter of 16).
// Wave w holds W_{r,i,n}[j*16..+16][w*256..+256] in VGPRs (24 bf16x8 frags).
// Per step: 4 waves K-split MFMA -> LDS reduce -> per-thread pointwise (1 cell/thread),
// publish bf16 h to double buffer, device-wide flag barrier.
__launch_bounds__(256, 1)
__global__ void k_recurrent(const unsigned short* __restrict__ wh,   // [3][1024][1024] bf16
                            const unsigned short* __restrict__ gr,
                            const unsigned short* __restrict__ gi,
                            const float* __restrict__ state,
                            const float* __restrict__ bias_nh,
                            unsigned short* __restrict__ hbuf,       // [2][64][1024] bf16
                            unsigned int* __restrict__ flags,        // [256]
                            float* __restrict__ out) {               // [512][64][1024] + [64][1024]
  __shared__ float red[4][3][256];

  int tid = threadIdx.x;
  int lane = tid & 63, w = tid >> 6;
  int wg = blockIdx.x;
  int j = wg & 63;
  int mb = wg >> 6;

  // persistent weight fragments (96 VGPRs)
  int frow = j * 16 + (lane & 15);
  int fk0 = w * 256 + ((lane >> 4) * 8);
  bf16x8 wf[3][8];
#pragma unroll
  for (int g = 0; g < 3; ++g)
#pragma unroll
    for (int s = 0; s < 8; ++s)
      wf[g][s] = *(const bf16x8*)(wh + ((long)g << 20) + (long)frow * 1024 + fk0 + s * 32);

  // per-thread pointwise cell
  int crow = tid >> 4, ccol = tid & 15;
  int brow = mb * 16 + crow;
  int colg = j * 16 + ccol;
  long cellofs = (long)brow * 1024 + colg;
  float h_local = clampf(state[cellofs]);
  float bnh = bias_nh[colg];

  // A-fragment (h) addressing for this lane
  long aofs = (long)(mb * 16 + (lane & 15)) * 1024 + fk0;

  for (int t = 0; t < NT; ++t) {
    const unsigned short* hsrc = hbuf + (long)(t & 1) * (NB * NH);
    bf16x8 af[8];
#pragma unroll
    for (int s = 0; s < 8; ++s)
      af[s] = *(const bf16x8*)(hsrc + aofs + s * 32);

    f32x4 acc[3] = {};
#pragma unroll
    for (int g = 0; g < 3; ++g)
#pragma unroll
      for (int s = 0; s < 8; ++s)
        acc[g] = __builtin_amdgcn_mfma_f32_16x16x32_bf16(af[s], wf[g][s], acc[g], 0, 0, 0);

    // stage partials: cell = (row)*16+col, row=(lane>>4)*4+r, col=lane&15
#pragma unroll
    for (int g = 0; g < 3; ++g)
#pragma unroll
      for (int r = 0; r < 4; ++r)
        red[w][g][((lane >> 4) * 4 + r) * 16 + (lane & 15)] = acc[g][r];
    __syncthreads();

    float pr = red[0][0][tid] + red[1][0][tid] + red[2][0][tid] + red[3][0][tid];
    float pi = red[0][1][tid] + red[1][1][tid] + red[2][1][tid] + red[3][1][tid];
    float pn = red[0][2][tid] + red[1][2][tid] + red[2][2][tid] + red[3][2][tid];

    long gofs = (long)t * (NB * NH) + cellofs;
    float grv = bf2f(gr[gofs]);
    float giv = bf2f(gi[gofs]);
    float gniv = out[gofs];  // pre-clamped x-path of n gate (written by k_gemm_x)

    float rg = 1.f / (1.f + __expf(-(pr + grv)));
    float ig = 1.f / (1.f + __expf(-(pi + giv)));
    float ng = tanhf(gniv + clampf(rg * (pn + bnh)));
    float s  = clampf(h_local) - ng;
    float hy = ng + clampf(ig * s);

    out[gofs] = hy;
    h_local = hy;
    hbuf[(long)((t + 1) & 1) * (NB * NH) + cellofs] = f2bf(hy);

    // ---- device-wide barrier (per-WG release flag, per-thread acquire poll) ----
    __threadfence();
    __syncthreads();
    if (tid == 0)
      __hip_atomic_store(&flags[wg], (unsigned)(t + 1), __ATOMIC_RELEASE, __HIP_MEMORY_SCOPE_AGENT);
    while (__hip_atomic_load(&flags[tid], __ATOMIC_ACQUIRE, __HIP_MEMORY_SCOPE_AGENT) < (unsigned)(t + 1))
      __builtin_amdgcn_s_sleep(2);
    __syncthreads();
  }

  // last hidden state
  out[(long)NT * (NB * NH) + cellofs] = h_local;
}

// ---------------------------------------------------------------------------
extern "C" void kernel_launch(void* const* d_in, const int* in_sizes, int n_in,
                              void* d_out, int out_size, void* d_ws, size_t ws_size,
                              hipStream_t stream) {
  const float* inputs = (const float*)d_in[0];
  const float* state  = (const float*)d_in[1];
  const float* wri = (const float*)d_in[2];
  const float* wii = (const float*)d_in[3];
  const float* wni = (const float*)d_in[4];
  const float* wrh = (const float*)d_in[5];
  const float* wih = (const float*)d_in[6];
  const float* wnh = (const float*)d_in[7];
  const float* br  = (const float*)d_in[8];
  const float* bi  = (const float*)d_in[9];
  const float* bni = (const float*)d_in[10];
  const float* bnh = (const float*)d_in[11];

  if (ws_size < WS_NEED) {
    fprintf(stderr, "kernel_launch: ws too small (%zu < %lu)\n", ws_size, WS_NEED);
    return;
  }

  char* ws = (char*)d_ws;
  unsigned int*   flags = (unsigned int*)(ws + OFF_FLAGS);
  unsigned short* hbuf  = (unsigned short*)(ws + OFF_HBUF);
  unsigned short* wcat  = (unsigned short*)(ws + OFF_WCAT);
  unsigned short* whp   = (unsigned short*)(ws + OFF_WH);
  unsigned short* grw   = (unsigned short*)(ws + OFF_GR);
  unsigned short* giw   = (unsigned short*)(ws + OFF_GI);
  float* out = (float*)d_out;

  hipMemsetAsync(flags, 0, NWG * sizeof(unsigned int), stream);
  k_convert_weights<<<512, 256, 0, stream>>>(wri, wii, wni, wrh, wih, wnh, wcat, whp);
  k_clamp_convert<<<64, 256, 0, stream>>>(state, hbuf, NB * NH);
  k_gemm_x<<<6144, 256, 0, stream>>>(inputs, wcat, grw, giw, out, br, bi, bni);
  k_recurrent<<<NWG, 256, 0, stream>>>(whp, grw, giw, state, bnh, hbuf, flags, out);
}

// Round 2
// 6611.316 us; speedup vs baseline: 3.5554x; 3.5554x over previous
//
#include <hip/hip_runtime.h>
#include <hip/hip_bf16.h>
#include <cstdio>

// QuantGRU: T=512, B=64, I=H=1024.
// k_gemm_x precomputes all x-projections (parallel GEMM, bf16 MFMA).
// k_recurrent: persistent 256-WG kernel; per-step barrier is now PER GROUP
// (64 WGs sharing batch-slice mb), relaxed-poll flags + single acquire fence.

typedef short bf16x8 __attribute__((ext_vector_type(8)));
typedef float f32x4 __attribute__((ext_vector_type(4)));

#define NT 512
#define NB 64
#define NH 1024
#define NWG 256

// ws layout (bytes)
#define OFF_FLAGS 0UL
#define OFF_HBUF  4096UL                                   // 2 x 64x1024 bf16 = 256KB
#define OFF_WCAT  (OFF_HBUF + 2UL * NB * NH * 2)           // 3072x1024 bf16 = 6MB (Wri|Wii|Wni)
#define OFF_WH    (OFF_WCAT + 3UL * NH * NH * 2)           // 3 x 1024x1024 bf16 = 6MB (Wrh,Wih,Wnh)
#define OFF_GR    (OFF_WH   + 3UL * NH * NH * 2)           // 32768x1024 bf16 = 64MB
#define OFF_GI    (OFF_GR   + (unsigned long)NT * NB * NH * 2)
#define WS_NEED   (OFF_GI   + (unsigned long)NT * NB * NH * 2)   // ~140.3 MB

__device__ __forceinline__ float clampf(float x) { return fminf(fmaxf(x, -1.f), 1.f); }

__device__ __forceinline__ unsigned short f2bf(float x) {
  __hip_bfloat16 h = __float2bfloat16(x);
  union { __hip_bfloat16 h; unsigned short u; } cv;
  cv.h = h;
  return cv.u;
}
__device__ __forceinline__ float bf2f(unsigned short u) {
  return __uint_as_float(((unsigned)u) << 16);
}
__device__ __forceinline__ float frcp(float x) { return __builtin_amdgcn_rcpf(x); }
__device__ __forceinline__ float fsigmoid(float x) { return frcp(1.f + __expf(-x)); }
__device__ __forceinline__ float ftanh(float z) { return 1.f - 2.f * frcp(1.f + __expf(2.f * z)); }

// ---------------- kernel 0a: weights f32 -> bf16 --------------------------
__global__ void k_convert_weights(const float* __restrict__ wri, const float* __restrict__ wii,
                                  const float* __restrict__ wni, const float* __restrict__ wrh,
                                  const float* __restrict__ wih, const float* __restrict__ wnh,
                                  unsigned short* __restrict__ wcat, unsigned short* __restrict__ wh) {
  const long total = 6L * 1024 * 1024;
  long stride = (long)gridDim.x * blockDim.x * 4;
  for (long i = ((long)blockIdx.x * blockDim.x + threadIdx.x) * 4; i < total; i += stride) {
    int m = (int)(i >> 20);              // which matrix
    long off = i & 1048575L;
    const float* srcs[6] = {wri, wii, wni, wrh, wih, wnh};
    float4 v = *(const float4*)(srcs[m] + off);
    ushort4 o;
    o.x = f2bf(v.x); o.y = f2bf(v.y); o.z = f2bf(v.z); o.w = f2bf(v.w);
    unsigned short* dst = (m < 3) ? (wcat + ((long)m << 20) + off)
                                  : (wh + ((long)(m - 3) << 20) + off);
    *(ushort4*)dst = o;
  }
}

// ---------------- kernel 0b: h0 = bf16(clamp(state)) ----------------------
__global__ void k_clamp_convert(const float* __restrict__ src, unsigned short* __restrict__ dst, int n) {
  int i = ((int)blockIdx.x * blockDim.x + threadIdx.x) * 4;
  if (i < n) {
    float4 v = *(const float4*)(src + i);
    ushort4 o;
    o.x = f2bf(clampf(v.x)); o.y = f2bf(clampf(v.y));
    o.z = f2bf(clampf(v.z)); o.w = f2bf(clampf(v.w));
    *(ushort4*)(dst + i) = o;
  }
}

// ---------------- kernel 1: input projections GEMM ------------------------
// C[m,n] = clamp(X[m,:]) . Wcat[n,:] + bias_g[n%1024]
// M=32768 (t*64+b), N=3072 (gate-major), K=1024. 128x128 tile, BK=64, 4 waves.
#define BK 64
__launch_bounds__(256)
__global__ void k_gemm_x(const float* __restrict__ A,              // X f32 [32768][1024]
                         const unsigned short* __restrict__ Bw,    // Wcat bf16 [3072][1024]
                         unsigned short* __restrict__ gr, unsigned short* __restrict__ gi,
                         float* __restrict__ gni,                  // = d_out plane [32768][1024]
                         const float* __restrict__ br, const float* __restrict__ bi,
                         const float* __restrict__ bni) {
  __shared__ unsigned short As[128 * BK];
  __shared__ unsigned short Bs[128 * BK];

  int bid = blockIdx.x;
  int bm = bid / 24, bn = bid % 24;
  int tid = threadIdx.x;
  int lane = tid & 63, w = tid >> 6;
  int wm = w >> 1, wn = w & 1;

  long arow0 = (long)bm * 128;
  long brow0 = (long)bn * 128;

  f32x4 acc[4][4] = {};

  for (int kt = 0; kt < 1024; kt += BK) {
    __syncthreads();
#pragma unroll
    for (int it = 0; it < 4; ++it) {
      int f = it * 2048 + tid * 8;
      int r = f >> 6, c = f & 63;
      // A: f32 -> clamp -> bf16 pack
      const float* ap = A + (arow0 + r) * 1024 + kt + c;
      float4 v0 = *(const float4*)ap;
      float4 v1 = *(const float4*)(ap + 4);
      int4 p;
      p.x = (int)(f2bf(clampf(v0.x)) | ((unsigned)f2bf(clampf(v0.y)) << 16));
      p.y = (int)(f2bf(clampf(v0.z)) | ((unsigned)f2bf(clampf(v0.w)) << 16));
      p.z = (int)(f2bf(clampf(v1.x)) | ((unsigned)f2bf(clampf(v1.y)) << 16));
      p.w = (int)(f2bf(clampf(v1.z)) | ((unsigned)f2bf(clampf(v1.w)) << 16));
      *(int4*)(&As[f]) = p;
      // B: bf16 straight copy
      *(int4*)(&Bs[f]) = *(const int4*)(Bw + (brow0 + r) * 1024 + kt + c);
    }
    __syncthreads();
#pragma unroll
    for (int ks = 0; ks < 2; ++ks) {
      bf16x8 a[4], b[4];
#pragma unroll
      for (int fm = 0; fm < 4; ++fm)
        a[fm] = *(const bf16x8*)(&As[(wm * 64 + fm * 16 + (lane & 15)) * BK + ks * 32 + (lane >> 4) * 8]);
#pragma unroll
      for (int fn = 0; fn < 4; ++fn)
        b[fn] = *(const bf16x8*)(&Bs[(wn * 64 + fn * 16 + (lane & 15)) * BK + ks * 32 + (lane >> 4) * 8]);
#pragma unroll
      for (int fm = 0; fm < 4; ++fm)
#pragma unroll
        for (int fn = 0; fn < 4; ++fn)
          acc[fm][fn] = __builtin_amdgcn_mfma_f32_16x16x32_bf16(a[fm], b[fn], acc[fm][fn], 0, 0, 0);
    }
  }

  int g = bn >> 3;  // 0:r 1:i 2:ni (uniform per block)
  const float* bias = (g == 0) ? br : (g == 1) ? bi : bni;
#pragma unroll
  for (int fm = 0; fm < 4; ++fm) {
    long m = arow0 + wm * 64 + fm * 16 + (lane >> 4) * 4;
#pragma unroll
    for (int fn = 0; fn < 4; ++fn) {
      long n = brow0 + wn * 64 + fn * 16 + (lane & 15);
      long colg = n & 1023;
      float bv = bias[colg];
#pragma unroll
      for (int r2 = 0; r2 < 4; ++r2) {
        float v = acc[fm][fn][r2] + bv;
        long idx = (m + r2) * 1024 + colg;
        if (g == 0)      gr[idx] = f2bf(v);
        else if (g == 1) gi[idx] = f2bf(v);
        else             gni[idx] = clampf(v);   // pre-clamped ni (includes bias)
      }
    }
  }
}

// ---------------- kernel 2: persistent recurrence -------------------------
// 256 WGs x 256 threads. WG = (j = wg&63 hidden slice of 16, mb = wg>>6 batch quarter).
// Barrier only spans the 64 WGs sharing mb (they produce the h-rows this WG reads).
// Poll = RELAXED agent loads (no cache inv); ONE acquire fence per step by wave 0.
__launch_bounds__(256, 1)
__global__ void k_recurrent(const unsigned short* __restrict__ wh,   // [3][1024][1024] bf16
                            const unsigned short* __restrict__ gr,
                            const unsigned short* __restrict__ gi,
                            const float* __restrict__ state,
                            const float* __restrict__ bias_nh,
                            unsigned short* __restrict__ hbuf,       // [2][64][1024] bf16
                            unsigned int* __restrict__ flags,        // [256]
                            float* __restrict__ out) {               // [512][64][1024] + [64][1024]
  __shared__ float red[4][3][256];

  int tid = threadIdx.x;
  int lane = tid & 63, w = tid >> 6;
  int wg = blockIdx.x;
  int j = wg & 63;
  int mb = wg >> 6;

  // persistent weight fragments (96 VGPRs)
  int frow = j * 16 + (lane & 15);
  int fk0 = w * 256 + ((lane >> 4) * 8);
  bf16x8 wf[3][8];
#pragma unroll
  for (int g = 0; g < 3; ++g)
#pragma unroll
    for (int s = 0; s < 8; ++s)
      wf[g][s] = *(const bf16x8*)(wh + ((long)g << 20) + (long)frow * 1024 + fk0 + s * 32);

  // per-thread pointwise cell
  int crow = tid >> 4, ccol = tid & 15;
  int brow = mb * 16 + crow;
  int colg = j * 16 + ccol;
  long cellofs = (long)brow * 1024 + colg;
  float h_local = clampf(state[cellofs]);
  float bnh = bias_nh[colg];

  // A-fragment (h) addressing for this lane
  long aofs = (long)(mb * 16 + (lane & 15)) * 1024 + fk0;

  // prefetch t=0 pointwise inputs
  float grv = bf2f(gr[cellofs]);
  float giv = bf2f(gi[cellofs]);
  float gniv = out[cellofs];

  const int flag_base = mb * 64;

#pragma unroll 1
  for (int t = 0; t < NT; ++t) {
    const unsigned short* hsrc = hbuf + (long)(t & 1) * (NB * NH);
    bf16x8 af[8];
#pragma unroll
    for (int s = 0; s < 8; ++s)
      af[s] = *(const bf16x8*)(hsrc + aofs + s * 32);

    f32x4 acc[3] = {};
#pragma unroll
    for (int g = 0; g < 3; ++g)
#pragma unroll
      for (int s = 0; s < 8; ++s)
        acc[g] = __builtin_amdgcn_mfma_f32_16x16x32_bf16(af[s], wf[g][s], acc[g], 0, 0, 0);

    // stage partials: cell = row*16+col, row=(lane>>4)*4+r, col=lane&15
#pragma unroll
    for (int g = 0; g < 3; ++g)
#pragma unroll
      for (int r = 0; r < 4; ++r)
        red[w][g][((lane >> 4) * 4 + r) * 16 + (lane & 15)] = acc[g][r];
    __syncthreads();

    float pr = red[0][0][tid] + red[1][0][tid] + red[2][0][tid] + red[3][0][tid];
    float pi = red[0][1][tid] + red[1][1][tid] + red[2][1][tid] + red[3][1][tid];
    float pn = red[0][2][tid] + red[1][2][tid] + red[2][2][tid] + red[3][2][tid];

    float rg = fsigmoid(pr + grv);
    float ig = fsigmoid(pi + giv);
    float ng = ftanh(gniv + clampf(rg * (pn + bnh)));
    float s  = clampf(h_local) - ng;
    float hy = ng + clampf(ig * s);

    long gofs = (long)t * (NB * NH) + cellofs;
    out[gofs] = hy;
    h_local = hy;
    hbuf[(long)((t + 1) & 1) * (NB * NH) + cellofs] = f2bf(hy);

    // ---- arrive: syncthreads drains all waves' stores to L2; release store
    //      by tid0 writes L2 back to the coherence point and publishes flag ----
    __syncthreads();
    if (tid == 0)
      __hip_atomic_store(&flags[wg], (unsigned)(t + 1), __ATOMIC_RELEASE, __HIP_MEMORY_SCOPE_AGENT);

    // prefetch next step's pointwise inputs (independent of the barrier)
    if (t + 1 < NT) {
      long g2 = (long)(t + 1) * (NB * NH) + cellofs;
      grv = bf2f(gr[g2]);
      giv = bf2f(gi[g2]);
      gniv = out[g2];
    }

    // ---- wait: wave 0 relaxed-polls the group's 64 flags (2 cache lines),
    //      then ONE acquire fence invalidates L1(+L2) for the whole CU ----
    if (w == 0) {
      unsigned tgt = (unsigned)(t + 1);
      while (__hip_atomic_load(&flags[flag_base + lane], __ATOMIC_RELAXED,
                               __HIP_MEMORY_SCOPE_AGENT) < tgt)
        __builtin_amdgcn_s_sleep(1);
      __builtin_amdgcn_fence(__ATOMIC_ACQUIRE, "agent");
    }
    __syncthreads();
  }

  // last hidden state
  out[(long)NT * (NB * NH) + cellofs] = h_local;
}

// ---------------------------------------------------------------------------
extern "C" void kernel_launch(void* const* d_in, const int* in_sizes, int n_in,
                              void* d_out, int out_size, void* d_ws, size_t ws_size,
                              hipStream_t stream) {
  const float* inputs = (const float*)d_in[0];
  const float* state  = (const float*)d_in[1];
  const float* wri = (const float*)d_in[2];
  const float* wii = (const float*)d_in[3];
  const float* wni = (const float*)d_in[4];
  const float* wrh = (const float*)d_in[5];
  const float* wih = (const float*)d_in[6];
  const float* wnh = (const float*)d_in[7];
  const float* br  = (const float*)d_in[8];
  const float* bi  = (const float*)d_in[9];
  const float* bni = (const float*)d_in[10];
  const float* bnh = (const float*)d_in[11];

  if (ws_size < WS_NEED) {
    fprintf(stderr, "kernel_launch: ws too small (%zu < %lu)\n", ws_size, WS_NEED);
    return;
  }

  char* ws = (char*)d_ws;
  unsigned int*   flags = (unsigned int*)(ws + OFF_FLAGS);
  unsigned short* hbuf  = (unsigned short*)(ws + OFF_HBUF);
  unsigned short* wcat  = (unsigned short*)(ws + OFF_WCAT);
  unsigned short* whp   = (unsigned short*)(ws + OFF_WH);
  unsigned short* grw   = (unsigned short*)(ws + OFF_GR);
  unsigned short* giw   = (unsigned short*)(ws + OFF_GI);
  float* out = (float*)d_out;

  hipMemsetAsync(flags, 0, 4096, stream);
  k_convert_weights<<<512, 256, 0, stream>>>(wri, wii, wni, wrh, wih, wnh, wcat, whp);
  k_clamp_convert<<<64, 256, 0, stream>>>(state, hbuf, NB * NH);
  k_gemm_x<<<6144, 256, 0, stream>>>(inputs, wcat, grw, giw, out, br, bi, bni);
  k_recurrent<<<NWG, 256, 0, stream>>>(whp, grw, giw, state, bnh, hbuf, flags, out);
}

// Round 3
// 3612.189 us; speedup vs baseline: 6.5074x; 1.8303x over previous
//
#include <hip/hip_runtime.h>
#include <hip/hip_bf16.h>
#include <cstdio>

// QuantGRU: T=512, B=64, I=H=1024.
// k_gemm_x precomputes all x-projections (parallel GEMM, bf16 MFMA).
// k_recurrent: persistent 256-WG kernel. Cross-WG data (hbuf,flags) uses
// explicit write-through (sc0 sc1) stores + cache-bypass loads, so NO
// per-step fences / L2 invalidates are needed at all.

typedef short bf16x8 __attribute__((ext_vector_type(8)));
typedef float f32x4 __attribute__((ext_vector_type(4)));
typedef int i32x4 __attribute__((ext_vector_type(4)));

#define NT 512
#define NB 64
#define NH 1024
#define NWG 256

// ws layout (bytes)
#define OFF_FLAGS 0UL
#define OFF_HBUF  4096UL                                   // 2 x 64x1024 bf16 = 256KB
#define OFF_WCAT  (OFF_HBUF + 2UL * NB * NH * 2)           // 3072x1024 bf16 = 6MB (Wri|Wii|Wni)
#define OFF_WH    (OFF_WCAT + 3UL * NH * NH * 2)           // 3 x 1024x1024 bf16 = 6MB (Wrh,Wih,Wnh)
#define OFF_GR    (OFF_WH   + 3UL * NH * NH * 2)           // 32768x1024 bf16 = 64MB
#define OFF_GI    (OFF_GR   + (unsigned long)NT * NB * NH * 2)
#define WS_NEED   (OFF_GI   + (unsigned long)NT * NB * NH * 2)   // ~140.3 MB

__device__ __forceinline__ float clampf(float x) { return fminf(fmaxf(x, -1.f), 1.f); }

__device__ __forceinline__ unsigned short f2bf(float x) {
  __hip_bfloat16 h = __float2bfloat16(x);
  union { __hip_bfloat16 h; unsigned short u; } cv;
  cv.h = h;
  return cv.u;
}
__device__ __forceinline__ float bf2f(unsigned short u) {
  return __uint_as_float(((unsigned)u) << 16);
}
__device__ __forceinline__ float frcp(float x) { return __builtin_amdgcn_rcpf(x); }
__device__ __forceinline__ float fsigmoid(float x) { return frcp(1.f + __expf(-x)); }
__device__ __forceinline__ float ftanh(float z) { return 1.f - 2.f * frcp(1.f + __expf(2.f * z)); }

// ---- cross-WG coherent primitives (meet at the mall, no cache maintenance) ----
__device__ __forceinline__ void load_h_bypass(const unsigned short* p, i32x4 a[8]) {
  asm volatile(
      "global_load_dwordx4 %0, %8, off sc0 sc1\n\t"
      "global_load_dwordx4 %1, %8, off offset:64 sc0 sc1\n\t"
      "global_load_dwordx4 %2, %8, off offset:128 sc0 sc1\n\t"
      "global_load_dwordx4 %3, %8, off offset:192 sc0 sc1\n\t"
      "global_load_dwordx4 %4, %8, off offset:256 sc0 sc1\n\t"
      "global_load_dwordx4 %5, %8, off offset:320 sc0 sc1\n\t"
      "global_load_dwordx4 %6, %8, off offset:384 sc0 sc1\n\t"
      "global_load_dwordx4 %7, %8, off offset:448 sc0 sc1\n\t"
      "s_waitcnt vmcnt(0)"
      : "=&v"(a[0]), "=&v"(a[1]), "=&v"(a[2]), "=&v"(a[3]),
        "=&v"(a[4]), "=&v"(a[5]), "=&v"(a[6]), "=&v"(a[7])
      : "v"(p)
      : "memory");
}
__device__ __forceinline__ void store_bf16_wt(unsigned short* p, unsigned v) {
  // write-through to coherence point; trailing drain so __syncthreads
  // afterwards implies global visibility of this store.
  asm volatile("global_store_short %0, %1, off sc0 sc1\n\ts_waitcnt vmcnt(0)"
               :: "v"(p), "v"(v) : "memory");
}
__device__ __forceinline__ void store_flag_wt(unsigned int* p, unsigned v) {
  asm volatile("s_waitcnt vmcnt(0)\n\tglobal_store_dword %0, %1, off sc0 sc1"
               :: "v"(p), "v"(v) : "memory");
}

// ---------------- kernel 0a: weights f32 -> bf16 --------------------------
__global__ void k_convert_weights(const float* __restrict__ wri, const float* __restrict__ wii,
                                  const float* __restrict__ wni, const float* __restrict__ wrh,
                                  const float* __restrict__ wih, const float* __restrict__ wnh,
                                  unsigned short* __restrict__ wcat, unsigned short* __restrict__ wh) {
  const long total = 6L * 1024 * 1024;
  long stride = (long)gridDim.x * blockDim.x * 4;
  for (long i = ((long)blockIdx.x * blockDim.x + threadIdx.x) * 4; i < total; i += stride) {
    int m = (int)(i >> 20);              // which matrix
    long off = i & 1048575L;
    const float* srcs[6] = {wri, wii, wni, wrh, wih, wnh};
    float4 v = *(const float4*)(srcs[m] + off);
    ushort4 o;
    o.x = f2bf(v.x); o.y = f2bf(v.y); o.z = f2bf(v.z); o.w = f2bf(v.w);
    unsigned short* dst = (m < 3) ? (wcat + ((long)m << 20) + off)
                                  : (wh + ((long)(m - 3) << 20) + off);
    *(ushort4*)dst = o;
  }
}

// ---------------- kernel 0b: h0 = bf16(clamp(state)) ----------------------
__global__ void k_clamp_convert(const float* __restrict__ src, unsigned short* __restrict__ dst, int n) {
  int i = ((int)blockIdx.x * blockDim.x + threadIdx.x) * 4;
  if (i < n) {
    float4 v = *(const float4*)(src + i);
    ushort4 o;
    o.x = f2bf(clampf(v.x)); o.y = f2bf(clampf(v.y));
    o.z = f2bf(clampf(v.z)); o.w = f2bf(clampf(v.w));
    *(ushort4*)(dst + i) = o;
  }
}

// ---------------- kernel 1: input projections GEMM ------------------------
// C[m,n] = clamp(X[m,:]) . Wcat[n,:] + bias_g[n%1024]
// M=32768 (t*64+b), N=3072 (gate-major), K=1024. 128x128 tile, BK=64, 4 waves.
#define BK 64
__launch_bounds__(256)
__global__ void k_gemm_x(const float* __restrict__ A,              // X f32 [32768][1024]
                         const unsigned short* __restrict__ Bw,    // Wcat bf16 [3072][1024]
                         unsigned short* __restrict__ gr, unsigned short* __restrict__ gi,
                         float* __restrict__ gni,                  // = d_out plane [32768][1024]
                         const float* __restrict__ br, const float* __restrict__ bi,
                         const float* __restrict__ bni) {
  __shared__ unsigned short As[128 * BK];
  __shared__ unsigned short Bs[128 * BK];

  int bid = blockIdx.x;
  int bm = bid / 24, bn = bid % 24;
  int tid = threadIdx.x;
  int lane = tid & 63, w = tid >> 6;
  int wm = w >> 1, wn = w & 1;

  long arow0 = (long)bm * 128;
  long brow0 = (long)bn * 128;

  f32x4 acc[4][4] = {};

  for (int kt = 0; kt < 1024; kt += BK) {
    __syncthreads();
#pragma unroll
    for (int it = 0; it < 4; ++it) {
      int f = it * 2048 + tid * 8;
      int r = f >> 6, c = f & 63;
      // A: f32 -> clamp -> bf16 pack
      const float* ap = A + (arow0 + r) * 1024 + kt + c;
      float4 v0 = *(const float4*)ap;
      float4 v1 = *(const float4*)(ap + 4);
      int4 p;
      p.x = (int)(f2bf(clampf(v0.x)) | ((unsigned)f2bf(clampf(v0.y)) << 16));
      p.y = (int)(f2bf(clampf(v0.z)) | ((unsigned)f2bf(clampf(v0.w)) << 16));
      p.z = (int)(f2bf(clampf(v1.x)) | ((unsigned)f2bf(clampf(v1.y)) << 16));
      p.w = (int)(f2bf(clampf(v1.z)) | ((unsigned)f2bf(clampf(v1.w)) << 16));
      *(int4*)(&As[f]) = p;
      // B: bf16 straight copy
      *(int4*)(&Bs[f]) = *(const int4*)(Bw + (brow0 + r) * 1024 + kt + c);
    }
    __syncthreads();
#pragma unroll
    for (int ks = 0; ks < 2; ++ks) {
      bf16x8 a[4], b[4];
#pragma unroll
      for (int fm = 0; fm < 4; ++fm)
        a[fm] = *(const bf16x8*)(&As[(wm * 64 + fm * 16 + (lane & 15)) * BK + ks * 32 + (lane >> 4) * 8]);
#pragma unroll
      for (int fn = 0; fn < 4; ++fn)
        b[fn] = *(const bf16x8*)(&Bs[(wn * 64 + fn * 16 + (lane & 15)) * BK + ks * 32 + (lane >> 4) * 8]);
#pragma unroll
      for (int fm = 0; fm < 4; ++fm)
#pragma unroll
        for (int fn = 0; fn < 4; ++fn)
          acc[fm][fn] = __builtin_amdgcn_mfma_f32_16x16x32_bf16(a[fm], b[fn], acc[fm][fn], 0, 0, 0);
    }
  }

  int g = bn >> 3;  // 0:r 1:i 2:ni (uniform per block)
  const float* bias = (g == 0) ? br : (g == 1) ? bi : bni;
#pragma unroll
  for (int fm = 0; fm < 4; ++fm) {
    long m = arow0 + wm * 64 + fm * 16 + (lane >> 4) * 4;
#pragma unroll
    for (int fn = 0; fn < 4; ++fn) {
      long n = brow0 + wn * 64 + fn * 16 + (lane & 15);
      long colg = n & 1023;
      float bv = bias[colg];
#pragma unroll
      for (int r2 = 0; r2 < 4; ++r2) {
        float v = acc[fm][fn][r2] + bv;
        long idx = (m + r2) * 1024 + colg;
        if (g == 0)      gr[idx] = f2bf(v);
        else if (g == 1) gi[idx] = f2bf(v);
        else             gni[idx] = clampf(v);   // pre-clamped ni (includes bias)
      }
    }
  }
}

// ---------------- kernel 2: persistent recurrence -------------------------
// 256 WGs x 256 threads. WG = (j = wg&63 hidden slice of 16, mb = wg>>6 batch quarter).
// Barrier spans only the 64 WGs sharing mb. hbuf+flags are write-through /
// cache-bypass -> zero per-step cache maintenance; L2 stays warm for gr/gi/gni.
__launch_bounds__(256, 1)
__global__ void k_recurrent(const unsigned short* __restrict__ wh,   // [3][1024][1024] bf16
                            const unsigned short* __restrict__ gr,
                            const unsigned short* __restrict__ gi,
                            const float* __restrict__ state,
                            const float* __restrict__ bias_nh,
                            unsigned short* __restrict__ hbuf,       // [2][64][1024] bf16
                            unsigned int* __restrict__ flags,        // [256]
                            float* __restrict__ out) {               // [512][64][1024] + [64][1024]
  __shared__ float red[4][3][256];

  int tid = threadIdx.x;
  int lane = tid & 63, w = tid >> 6;
  int wg = blockIdx.x;
  int j = wg & 63;
  int mb = wg >> 6;

  // persistent weight fragments (96 VGPRs)
  int frow = j * 16 + (lane & 15);
  int fk0 = w * 256 + ((lane >> 4) * 8);
  bf16x8 wf[3][8];
#pragma unroll
  for (int g = 0; g < 3; ++g)
#pragma unroll
    for (int s = 0; s < 8; ++s)
      wf[g][s] = *(const bf16x8*)(wh + ((long)g << 20) + (long)frow * 1024 + fk0 + s * 32);

  // per-thread pointwise cell
  int crow = tid >> 4, ccol = tid & 15;
  int brow = mb * 16 + crow;
  int colg = j * 16 + ccol;
  long cellofs = (long)brow * 1024 + colg;
  float h_local = clampf(state[cellofs]);
  float bnh = bias_nh[colg];

  // A-fragment (h) addressing for this lane
  long aofs = (long)(mb * 16 + (lane & 15)) * 1024 + fk0;

  // prefetch t=0 pointwise inputs
  float grv = bf2f(gr[cellofs]);
  float giv = bf2f(gi[cellofs]);
  float gniv = out[cellofs];

  const int flag_base = mb * 64;

#pragma unroll 1
  for (int t = 0; t < NT; ++t) {
    // h fragments: cache-bypass loads (data written write-through by producers;
    // t=0 data flushed to mall by k_clamp_convert's dispatch-end release)
    i32x4 afi[8];
    load_h_bypass(hbuf + (long)(t & 1) * (NB * NH) + aofs, afi);

    f32x4 acc[3] = {};
#pragma unroll
    for (int s = 0; s < 8; ++s) {
      bf16x8 a = __builtin_bit_cast(bf16x8, afi[s]);
#pragma unroll
      for (int g = 0; g < 3; ++g)
        acc[g] = __builtin_amdgcn_mfma_f32_16x16x32_bf16(a, wf[g][s], acc[g], 0, 0, 0);
    }

    // stage partials: cell = row*16+col, row=(lane>>4)*4+r, col=lane&15
#pragma unroll
    for (int g = 0; g < 3; ++g)
#pragma unroll
      for (int r = 0; r < 4; ++r)
        red[w][g][((lane >> 4) * 4 + r) * 16 + (lane & 15)] = acc[g][r];
    __syncthreads();

    float pr = red[0][0][tid] + red[1][0][tid] + red[2][0][tid] + red[3][0][tid];
    float pi = red[0][1][tid] + red[1][1][tid] + red[2][1][tid] + red[3][1][tid];
    float pn = red[0][2][tid] + red[1][2][tid] + red[2][2][tid] + red[3][2][tid];

    float rg = fsigmoid(pr + grv);
    float ig = fsigmoid(pi + giv);
    float ng = ftanh(gniv + clampf(rg * (pn + bnh)));
    float s  = clampf(h_local) - ng;
    float hy = ng + clampf(ig * s);

    long gofs = (long)t * (NB * NH) + cellofs;
    out[gofs] = hy;
    h_local = hy;
    // publish h(t+1) write-through (includes vmcnt drain)
    store_bf16_wt(hbuf + (long)((t + 1) & 1) * (NB * NH) + cellofs, (unsigned)f2bf(hy));

    // all waves' WT stores drained at this barrier
    __syncthreads();

    if (t + 1 < NT) {
      unsigned tgt = (unsigned)(t + 1);
      if (tid == 0) store_flag_wt(&flags[wg], tgt);

      // prefetch next step's pointwise inputs during the wait (cached, private)
      long g2 = (long)(t + 1) * (NB * NH) + cellofs;
      grv = bf2f(gr[g2]);
      giv = bf2f(gi[g2]);
      gniv = out[g2];

      // every wave polls all 64 group flags (lane l -> flag l); no extra barrier:
      // observing flag==t+1 implies that WG passed its post-store barrier.
      while (__hip_atomic_load(&flags[flag_base + lane], __ATOMIC_RELAXED,
                               __HIP_MEMORY_SCOPE_AGENT) < tgt)
        __builtin_amdgcn_s_sleep(1);
    }
  }

  // last hidden state
  out[(long)NT * (NB * NH) + cellofs] = h_local;
}

// ---------------------------------------------------------------------------
extern "C" void kernel_launch(void* const* d_in, const int* in_sizes, int n_in,
                              void* d_out, int out_size, void* d_ws, size_t ws_size,
                              hipStream_t stream) {
  const float* inputs = (const float*)d_in[0];
  const float* state  = (const float*)d_in[1];
  const float* wri = (const float*)d_in[2];
  const float* wii = (const float*)d_in[3];
  const float* wni = (const float*)d_in[4];
  const float* wrh = (const float*)d_in[5];
  const float* wih = (const float*)d_in[6];
  const float* wnh = (const float*)d_in[7];
  const float* br  = (const float*)d_in[8];
  const float* bi  = (const float*)d_in[9];
  const float* bni = (const float*)d_in[10];
  const float* bnh = (const float*)d_in[11];

  if (ws_size < WS_NEED) {
    fprintf(stderr, "kernel_launch: ws too small (%zu < %lu)\n", ws_size, WS_NEED);
    return;
  }

  char* ws = (char*)d_ws;
  unsigned int*   flags = (unsigned int*)(ws + OFF_FLAGS);
  unsigned short* hbuf  = (unsigned short*)(ws + OFF_HBUF);
  unsigned short* wcat  = (unsigned short*)(ws + OFF_WCAT);
  unsigned short* whp   = (unsigned short*)(ws + OFF_WH);
  unsigned short* grw   = (unsigned short*)(ws + OFF_GR);
  unsigned short* giw   = (unsigned short*)(ws + OFF_GI);
  float* out = (float*)d_out;

  hipMemsetAsync(flags, 0, 4096, stream);
  k_convert_weights<<<512, 256, 0, stream>>>(wri, wii, wni, wrh, wih, wnh, wcat, whp);
  k_clamp_convert<<<64, 256, 0, stream>>>(state, hbuf, NB * NH);
  k_gemm_x<<<6144, 256, 0, stream>>>(inputs, wcat, grw, giw, out, br, bi, bni);
  k_recurrent<<<NWG, 256, 0, stream>>>(whp, grw, giw, state, bnh, hbuf, flags, out);
}

// Round 6
// 3004.754 us; speedup vs baseline: 7.8229x; 1.2022x over previous
//
#include <hip/hip_runtime.h>
#include <hip/hip_bf16.h>
#include <cstdio>

// QuantGRU: T=512, B=64, I=H=1024.
// k_gemm_x precomputes all x-projections (parallel GEMM, bf16 MFMA).
// k_recurrent: persistent 256-WG kernel. h exchange = TAGGED DATA WORDS:
// u32 = (bf16(h)<<16)|step. Producers fire one WT (sc0 sc1) store; consumers
// poll exactly the words they need at the mall (sc0 sc1 loads) until tags
// match, then repack via v_perm. One mall round-trip per step, no flags,
// no fences, no barrier-drain on the critical path. (r3-proven visibility.)

typedef short bf16x8 __attribute__((ext_vector_type(8)));
typedef float f32x4 __attribute__((ext_vector_type(4)));
typedef int i32x4 __attribute__((ext_vector_type(4)));

#define NT 512
#define NB 64
#define NH 1024

// ws layout (bytes)
#define OFF_HBUF  4096UL                                   // 2 x 64x1024 u32 = 512KB (tagged)
#define OFF_WCAT  (OFF_HBUF + 2UL * NB * NH * 4)           // 3072x1024 bf16 (Wri|Wii|Wni)
#define OFF_WH    (OFF_WCAT + 3UL * NH * NH * 2)           // 3 x 1024x1024 bf16 (Wrh,Wih,Wnh)
#define OFF_GR    (OFF_WH   + 3UL * NH * NH * 2)           // 32768x1024 bf16
#define OFF_GI    (OFF_GR   + (unsigned long)NT * NB * NH * 2)
#define WS_NEED   (OFF_GI   + (unsigned long)NT * NB * NH * 2)   // ~140.6 MB

__device__ __forceinline__ float clampf(float x) { return fminf(fmaxf(x, -1.f), 1.f); }

__device__ __forceinline__ unsigned short f2bf(float x) {
  __hip_bfloat16 h = __float2bfloat16(x);
  union { __hip_bfloat16 h; unsigned short u; } cv;
  cv.h = h;
  return cv.u;
}
__device__ __forceinline__ float bf2f(unsigned short u) {
  return __uint_as_float(((unsigned)u) << 16);
}
__device__ __forceinline__ float frcp(float x) { return __builtin_amdgcn_rcpf(x); }
__device__ __forceinline__ float fsigmoid(float x) { return frcp(1.f + __expf(-x)); }
__device__ __forceinline__ float ftanh(float z) { return 1.f - 2.f * frcp(1.f + __expf(2.f * z)); }

// 16x dwordx4 tagged-word loads, straight from the mall (r3-proven sc0 sc1).
__device__ __forceinline__ void load_h_tagged(const unsigned int* p, i32x4 a[16]) {
  asm volatile(
      "global_load_dwordx4 %0, %16, off sc0 sc1\n\t"
      "global_load_dwordx4 %1, %16, off offset:16 sc0 sc1\n\t"
      "global_load_dwordx4 %2, %16, off offset:128 sc0 sc1\n\t"
      "global_load_dwordx4 %3, %16, off offset:144 sc0 sc1\n\t"
      "global_load_dwordx4 %4, %16, off offset:256 sc0 sc1\n\t"
      "global_load_dwordx4 %5, %16, off offset:272 sc0 sc1\n\t"
      "global_load_dwordx4 %6, %16, off offset:384 sc0 sc1\n\t"
      "global_load_dwordx4 %7, %16, off offset:400 sc0 sc1\n\t"
      "global_load_dwordx4 %8, %16, off offset:512 sc0 sc1\n\t"
      "global_load_dwordx4 %9, %16, off offset:528 sc0 sc1\n\t"
      "global_load_dwordx4 %10, %16, off offset:640 sc0 sc1\n\t"
      "global_load_dwordx4 %11, %16, off offset:656 sc0 sc1\n\t"
      "global_load_dwordx4 %12, %16, off offset:768 sc0 sc1\n\t"
      "global_load_dwordx4 %13, %16, off offset:784 sc0 sc1\n\t"
      "global_load_dwordx4 %14, %16, off offset:896 sc0 sc1\n\t"
      "global_load_dwordx4 %15, %16, off offset:912 sc0 sc1\n\t"
      "s_waitcnt vmcnt(0)"
      : "=&v"(a[0]), "=&v"(a[1]), "=&v"(a[2]), "=&v"(a[3]),
        "=&v"(a[4]), "=&v"(a[5]), "=&v"(a[6]), "=&v"(a[7]),
        "=&v"(a[8]), "=&v"(a[9]), "=&v"(a[10]), "=&v"(a[11]),
        "=&v"(a[12]), "=&v"(a[13]), "=&v"(a[14]), "=&v"(a[15])
      : "v"(p)
      : "memory");
}
// fire-and-forget write-through store (r3-proven visibility path)
__device__ __forceinline__ void store_u32_wt(unsigned int* p, unsigned v) {
  asm volatile("global_store_dword %0, %1, off sc0 sc1" :: "v"(p), "v"(v) : "memory");
}

// ---------------- kernel 0: weights f32 -> bf16 ---------------------------
__global__ void k_convert_weights(const float* __restrict__ wri, const float* __restrict__ wii,
                                  const float* __restrict__ wni, const float* __restrict__ wrh,
                                  const float* __restrict__ wih, const float* __restrict__ wnh,
                                  unsigned short* __restrict__ wcat, unsigned short* __restrict__ wh) {
  const long total = 6L * 1024 * 1024;
  long stride = (long)gridDim.x * blockDim.x * 4;
  for (long i = ((long)blockIdx.x * blockDim.x + threadIdx.x) * 4; i < total; i += stride) {
    int m = (int)(i >> 20);              // which matrix
    long off = i & 1048575L;
    const float* srcs[6] = {wri, wii, wni, wrh, wih, wnh};
    float4 v = *(const float4*)(srcs[m] + off);
    ushort4 o;
    o.x = f2bf(v.x); o.y = f2bf(v.y); o.z = f2bf(v.z); o.w = f2bf(v.w);
    unsigned short* dst = (m < 3) ? (wcat + ((long)m << 20) + off)
                                  : (wh + ((long)(m - 3) << 20) + off);
    *(ushort4*)dst = o;
  }
}

// ---------------- kernel 1: input projections GEMM ------------------------
#define BK 64
__launch_bounds__(256)
__global__ void k_gemm_x(const float* __restrict__ A,              // X f32 [32768][1024]
                         const unsigned short* __restrict__ Bw,    // Wcat bf16 [3072][1024]
                         unsigned short* __restrict__ gr, unsigned short* __restrict__ gi,
                         float* __restrict__ gni,                  // = d_out plane [32768][1024]
                         const float* __restrict__ br, const float* __restrict__ bi,
                         const float* __restrict__ bni) {
  __shared__ unsigned short As[128 * BK];
  __shared__ unsigned short Bs[128 * BK];

  int bid = blockIdx.x;
  int bm = bid / 24, bn = bid % 24;
  int tid = threadIdx.x;
  int lane = tid & 63, w = tid >> 6;
  int wm = w >> 1, wn = w & 1;

  long arow0 = (long)bm * 128;
  long brow0 = (long)bn * 128;

  f32x4 acc[4][4] = {};

  for (int kt = 0; kt < 1024; kt += BK) {
    __syncthreads();
#pragma unroll
    for (int it = 0; it < 4; ++it) {
      int f = it * 2048 + tid * 8;
      int r = f >> 6, c = f & 63;
      const float* ap = A + (arow0 + r) * 1024 + kt + c;
      float4 v0 = *(const float4*)ap;
      float4 v1 = *(const float4*)(ap + 4);
      int4 p;
      p.x = (int)(f2bf(clampf(v0.x)) | ((unsigned)f2bf(clampf(v0.y)) << 16));
      p.y = (int)(f2bf(clampf(v0.z)) | ((unsigned)f2bf(clampf(v0.w)) << 16));
      p.z = (int)(f2bf(clampf(v1.x)) | ((unsigned)f2bf(clampf(v1.y)) << 16));
      p.w = (int)(f2bf(clampf(v1.z)) | ((unsigned)f2bf(clampf(v1.w)) << 16));
      *(int4*)(&As[f]) = p;
      *(int4*)(&Bs[f]) = *(const int4*)(Bw + (brow0 + r) * 1024 + kt + c);
    }
    __syncthreads();
#pragma unroll
    for (int ks = 0; ks < 2; ++ks) {
      bf16x8 a[4], b[4];
#pragma unroll
      for (int fm = 0; fm < 4; ++fm)
        a[fm] = *(const bf16x8*)(&As[(wm * 64 + fm * 16 + (lane & 15)) * BK + ks * 32 + (lane >> 4) * 8]);
#pragma unroll
      for (int fn = 0; fn < 4; ++fn)
        b[fn] = *(const bf16x8*)(&Bs[(wn * 64 + fn * 16 + (lane & 15)) * BK + ks * 32 + (lane >> 4) * 8]);
#pragma unroll
      for (int fm = 0; fm < 4; ++fm)
#pragma unroll
        for (int fn = 0; fn < 4; ++fn)
          acc[fm][fn] = __builtin_amdgcn_mfma_f32_16x16x32_bf16(a[fm], b[fn], acc[fm][fn], 0, 0, 0);
    }
  }

  int g = bn >> 3;  // 0:r 1:i 2:ni (uniform per block)
  const float* bias = (g == 0) ? br : (g == 1) ? bi : bni;
#pragma unroll
  for (int fm = 0; fm < 4; ++fm) {
    long m = arow0 + wm * 64 + fm * 16 + (lane >> 4) * 4;
#pragma unroll
    for (int fn = 0; fn < 4; ++fn) {
      long n = brow0 + wn * 64 + fn * 16 + (lane & 15);
      long colg = n & 1023;
      float bv = bias[colg];
#pragma unroll
      for (int r2 = 0; r2 < 4; ++r2) {
        float v = acc[fm][fn][r2] + bv;
        long idx = (m + r2) * 1024 + colg;
        if (g == 0)      gr[idx] = f2bf(v);
        else if (g == 1) gi[idx] = f2bf(v);
        else             gni[idx] = clampf(v);   // pre-clamped ni (includes bias)
      }
    }
  }
}

// ---------------- kernel 2: persistent recurrence (tagged h words) --------
// 256 WGs x 256 threads. WG = (j = wg&63 hidden cols j*16..+16, mb = wg>>6
// batch rows mb*16..+16). Wave w K-slice = w*256..+256. Per step: MFMA,
// LDS reduce, pointwise, tagged WT h store, per-wave data-poll of the exact
// 64 words the next MFMA needs.
__launch_bounds__(256, 1)
__global__ void k_recurrent(const unsigned short* __restrict__ wh,   // [3][1024][1024] bf16
                            const unsigned short* __restrict__ gr,
                            const unsigned short* __restrict__ gi,
                            const float* __restrict__ state,
                            const float* __restrict__ bias_nh,
                            unsigned int* __restrict__ hbuf,         // [2][64][1024] u32 tagged
                            float* __restrict__ out) {               // [512][64][1024] + [64][1024]
  __shared__ float red[4][3][256];

  int tid = threadIdx.x;
  int lane = tid & 63, w = tid >> 6;
  int wg = blockIdx.x;
  int j = wg & 63;
  int mb = wg >> 6;

  // persistent weight fragments (96 VGPRs)
  int frow = j * 16 + (lane & 15);
  int fk0 = w * 256 + ((lane >> 4) * 8);
  bf16x8 wf[3][8];
#pragma unroll
  for (int g = 0; g < 3; ++g)
#pragma unroll
    for (int s = 0; s < 8; ++s)
      wf[g][s] = *(const bf16x8*)(wh + ((long)g << 20) + (long)frow * 1024 + fk0 + s * 32);

  // per-thread pointwise cell
  int crow = tid >> 4, ccol = tid & 15;
  int brow = mb * 16 + crow;
  int colg = j * 16 + ccol;
  long cellofs = (long)brow * 1024 + colg;
  float h_local = clampf(state[cellofs]);
  float bnh = bias_nh[colg];

  // A-fragment (h) addressing for this lane
  int arow = mb * 16 + (lane & 15);
  long abase = (long)arow * 1024 + fk0;   // u32/bf16 element offset

  // t=0 A-fragment straight from clamp(state), packed bf16
  i32x4 afi[8];
#pragma unroll
  for (int s = 0; s < 8; ++s) {
    const float* sp = state + abase + s * 32;
    float4 v0 = *(const float4*)sp;
    float4 v1 = *(const float4*)(sp + 4);
    i32x4 q;
    q[0] = (int)(f2bf(clampf(v0.x)) | ((unsigned)f2bf(clampf(v0.y)) << 16));
    q[1] = (int)(f2bf(clampf(v0.z)) | ((unsigned)f2bf(clampf(v0.w)) << 16));
    q[2] = (int)(f2bf(clampf(v1.x)) | ((unsigned)f2bf(clampf(v1.y)) << 16));
    q[3] = (int)(f2bf(clampf(v1.z)) | ((unsigned)f2bf(clampf(v1.w)) << 16));
    afi[s] = q;
  }

  // prefetch t=0 pointwise inputs
  float grv = bf2f(gr[cellofs]);
  float giv = bf2f(gi[cellofs]);
  float gniv = out[cellofs];

#pragma unroll 1
  for (int t = 0; t < NT; ++t) {
    f32x4 acc[3] = {};
#pragma unroll
    for (int s = 0; s < 8; ++s) {
      bf16x8 a = __builtin_bit_cast(bf16x8, afi[s]);
#pragma unroll
      for (int g = 0; g < 3; ++g)
        acc[g] = __builtin_amdgcn_mfma_f32_16x16x32_bf16(a, wf[g][s], acc[g], 0, 0, 0);
    }

    // stage partials: cell = row*16+col, row=(lane>>4)*4+r, col=lane&15
#pragma unroll
    for (int g = 0; g < 3; ++g)
#pragma unroll
      for (int r = 0; r < 4; ++r)
        red[w][g][((lane >> 4) * 4 + r) * 16 + (lane & 15)] = acc[g][r];
    __syncthreads();

    float pr = red[0][0][tid] + red[1][0][tid] + red[2][0][tid] + red[3][0][tid];
    float pi = red[0][1][tid] + red[1][1][tid] + red[2][1][tid] + red[3][1][tid];
    float pn = red[0][2][tid] + red[1][2][tid] + red[2][2][tid] + red[3][2][tid];
    __syncthreads();   // red[] free for next iteration (LDS-only barrier)

    float rg = fsigmoid(pr + grv);
    float ig = fsigmoid(pi + giv);
    float ng = ftanh(gniv + clampf(rg * (pn + bnh)));
    float sx = clampf(h_local) - ng;
    float hy = ng + clampf(ig * sx);

    long gofs = (long)t * (NB * NH) + cellofs;
    out[gofs] = hy;
    h_local = hy;

    unsigned tgt = (unsigned)(t + 1);
    // publish tagged h(t+1): single u32, fire-and-forget write-through
    store_u32_wt(hbuf + (long)(tgt & 1) * (NB * NH) + cellofs,
                 ((unsigned)f2bf(hy) << 16) | tgt);

    if (t + 1 < NT) {
      // prefetch next step's pointwise inputs (private, cached)
      long g2ofs = (long)tgt * (NB * NH) + cellofs;
      grv = bf2f(gr[g2ofs]);
      giv = bf2f(gi[g2ofs]);
      gniv = out[g2ofs];

      // per-wave data poll: re-load the 64 words this wave's MFMA needs
      // until every embedded tag == t+1. One mall RT in the common case.
      const unsigned int* hp = hbuf + (long)(tgt & 1) * (NB * NH) + abase;
      i32x4 raw[16];
      for (unsigned iter = 0;; ++iter) {
        load_h_tagged(hp, raw);
        unsigned mn = 0xFFFFFFFFu;
#pragma unroll
        for (int q = 0; q < 16; ++q)
#pragma unroll
          for (int e = 0; e < 4; ++e)
            mn = min(mn, ((unsigned)raw[q][e]) & 0xFFFFu);
        if (__all((int)(mn >= tgt)) || iter > (1u << 22)) break;
        __builtin_amdgcn_s_sleep(1);
      }
      // repack tagged u32 pairs -> bf16x8 fragments (hi16 halves)
#pragma unroll
      for (int s = 0; s < 8; ++s) {
        i32x4 q;
        q[0] = (int)__builtin_amdgcn_perm((unsigned)raw[2 * s][1], (unsigned)raw[2 * s][0], 0x07060302u);
        q[1] = (int)__builtin_amdgcn_perm((unsigned)raw[2 * s][3], (unsigned)raw[2 * s][2], 0x07060302u);
        q[2] = (int)__builtin_amdgcn_perm((unsigned)raw[2 * s + 1][1], (unsigned)raw[2 * s + 1][0], 0x07060302u);
        q[3] = (int)__builtin_amdgcn_perm((unsigned)raw[2 * s + 1][3], (unsigned)raw[2 * s + 1][2], 0x07060302u);
        afi[s] = q;
      }
    }
  }

  // last hidden state
  out[(long)NT * (NB * NH) + cellofs] = h_local;
}

// ---------------------------------------------------------------------------
extern "C" void kernel_launch(void* const* d_in, const int* in_sizes, int n_in,
                              void* d_out, int out_size, void* d_ws, size_t ws_size,
                              hipStream_t stream) {
  const float* inputs = (const float*)d_in[0];
  const float* state  = (const float*)d_in[1];
  const float* wri = (const float*)d_in[2];
  const float* wii = (const float*)d_in[3];
  const float* wni = (const float*)d_in[4];
  const float* wrh = (const float*)d_in[5];
  const float* wih = (const float*)d_in[6];
  const float* wnh = (const float*)d_in[7];
  const float* br  = (const float*)d_in[8];
  const float* bi  = (const float*)d_in[9];
  const float* bni = (const float*)d_in[10];
  const float* bnh = (const float*)d_in[11];

  if (ws_size < WS_NEED) {
    fprintf(stderr, "kernel_launch: ws too small (%zu < %lu)\n", ws_size, WS_NEED);
    return;
  }

  char* ws = (char*)d_ws;
  unsigned int*   hbuf  = (unsigned int*)(ws + OFF_HBUF);
  unsigned short* wcat  = (unsigned short*)(ws + OFF_WCAT);
  unsigned short* whp   = (unsigned short*)(ws + OFF_WH);
  unsigned short* grw   = (unsigned short*)(ws + OFF_GR);
  unsigned short* giw   = (unsigned short*)(ws + OFF_GI);
  float* out = (float*)d_out;

  // zero tag region every launch (stale tags from prior replays must die)
  hipMemsetAsync(ws, 0, OFF_WCAT, stream);
  k_convert_weights<<<512, 256, 0, stream>>>(wri, wii, wni, wrh, wih, wnh, wcat, whp);
  k_gemm_x<<<6144, 256, 0, stream>>>(inputs, wcat, grw, giw, out, br, bi, bni);
  k_recurrent<<<256, 256, 0, stream>>>(whp, grw, giw, state, bnh, hbuf, out);
}